// Round 8
// baseline (67503.076 us; speedup 1.0000x reference)
//
#include <hip/hip_runtime.h>

// Recurrent spiking LIF network: T=64, B=32, NE=4096, NI=1024, N=5120.
// Spikes exactly {0,1}; fp64 accumulation => spike-identical to the fp64
// numpy reference (verified rounds 2/5/6/7: absmax 0.0).
//
// Round-8: round-2 structure + 2 output neurons per thread.
//  - LDS-pipe analysis: round 2's 1 ds_read_b128 per 4 FMAs = 64us/step of
//    per-CU LDS time (the real bound). 2 n/thread -> 8 FMAs per b128 ->
//    32us LDS, ~27us VALU: balanced.
//  - thread t owns nA = bx*128+t (always E-target) and nB = nA+2560.
//  - JH=32 (all batches), no z-split (round-7 regression: 2x weight
//    readers + write amplification). Partial write pattern = round 2's
//    (measured exactly 41MB).
//  - block 128 (2 waves), grid (20, G); acc 64 x fp64 = 128 VGPR.

#define NE 4096
#define NI 1024
#define NN 5120
#define HN 2560      // NN/2
#define BB 32
#define CHUNK 160    // k-elements per LDS stage: 32*160*4 = 20 KB

// ---------------- matvec partial kernel ----------------
// grid: (HN/128, G), block 128. Thread owns neurons {nA, nA+2560},
// accumulates 2x32 fp64 over KR = NN/G sources.
template <int KR>
__global__ __launch_bounds__(128, 2) void mv_kernel(
    const float* __restrict__ W_ee, const float* __restrict__ W_ei,
    const float* __restrict__ W_ie, const float* __restrict__ W_ii,
    const float* __restrict__ sd,    // [BB][NN] spikes fp32 (0.0/1.0)
    double* __restrict__ partial)    // [G][BB][NN]
{
    __shared__ float s_l[BB][CHUNK];
    const int t = threadIdx.x;                 // 0..127
    const int nA = blockIdx.x * 128 + t;       // 0..2559  (< NE: E-target)
    const int nB = nA + HN;                    // 2560..5119 (mixed targets)
    const int kb0 = blockIdx.y * KR;

    double accA[BB], accB[BB];
#pragma unroll
    for (int j = 0; j < BB; ++j) { accA[j] = 0.0; accB[j] = 0.0; }

    // target-row pointers (source-E and source-I blocks of W)
    const float* __restrict__ rEA = W_ee + (size_t)nA * NE;   // nA < NE always
    const float* __restrict__ rIA = W_ie + (size_t)nA * NI;
    const float* __restrict__ rEB = (nB < NE) ? (W_ee + (size_t)nB * NE)
                                              : (W_ei + (size_t)(nB - NE) * NE);
    const float* __restrict__ rIB = (nB < NE) ? (W_ie + (size_t)nB * NI)
                                              : (W_ii + (size_t)(nB - NE) * NI);

    for (int pass = 0; pass < KR / CHUNK; ++pass) {
        const int kb = kb0 + pass * CHUNK;

        if (pass) __syncthreads();
        // stage 32x160 fp32 spikes, float4-vectorized (1280 quads / 128 thr)
        for (int f = t; f < BB * (CHUNK / 4); f += 128) {
            const int j = f / (CHUNK / 4);
            const int q = f - j * (CHUNK / 4);
            *reinterpret_cast<float4*>(&s_l[j][q * 4]) =
                *reinterpret_cast<const float4*>(sd + (size_t)j * NN + kb + q * 4);
        }
        __syncthreads();

        int aEnd = NE - kb;                    // E/I source boundary
        if (aEnd < 0) aEnd = 0;
        if (aEnd > CHUNK) aEnd = CHUNK;        // always a multiple of 4

        // ---- excitatory sources ----
        for (int kk = 0; kk < aEnd; kk += 4) {
            const float4 wa = *reinterpret_cast<const float4*>(rEA + kb + kk);
            const float4 wb = *reinterpret_cast<const float4*>(rEB + kb + kk);
            const double wa0 = (double)wa.x, wa1 = (double)wa.y,
                         wa2 = (double)wa.z, wa3 = (double)wa.w;
            const double wb0 = (double)wb.x, wb1 = (double)wb.y,
                         wb2 = (double)wb.z, wb3 = (double)wb.w;
#pragma unroll
            for (int j = 0; j < BB; ++j) {
                const float4 sv = *reinterpret_cast<const float4*>(&s_l[j][kk]);
                const double s0 = (double)sv.x, s1 = (double)sv.y,
                             s2 = (double)sv.z, s3 = (double)sv.w;
                accA[j] += wa0 * s0 + wa1 * s1 + wa2 * s2 + wa3 * s3;
                accB[j] += wb0 * s0 + wb1 * s1 + wb2 * s2 + wb3 * s3;
            }
        }
        // ---- inhibitory sources ----
        for (int kk = aEnd; kk < CHUNK; kk += 4) {
            const int ki = kb + kk - NE;
            const float4 wa = *reinterpret_cast<const float4*>(rIA + ki);
            const float4 wb = *reinterpret_cast<const float4*>(rIB + ki);
            const double wa0 = (double)wa.x, wa1 = (double)wa.y,
                         wa2 = (double)wa.z, wa3 = (double)wa.w;
            const double wb0 = (double)wb.x, wb1 = (double)wb.y,
                         wb2 = (double)wb.z, wb3 = (double)wb.w;
#pragma unroll
            for (int j = 0; j < BB; ++j) {
                const float4 sv = *reinterpret_cast<const float4*>(&s_l[j][kk]);
                const double s0 = (double)sv.x, s1 = (double)sv.y,
                             s2 = (double)sv.z, s3 = (double)sv.w;
                accA[j] += wa0 * s0 + wa1 * s1 + wa2 * s2 + wa3 * s3;
                accB[j] += wb0 * s0 + wb1 * s1 + wb2 * s2 + wb3 * s3;
            }
        }
    }

#pragma unroll
    for (int j = 0; j < BB; ++j) {
        const size_t base = ((size_t)blockIdx.y * BB + j) * NN;
        partial[base + nA] = accA[j];
        partial[base + nB] = accB[j];
    }
}

// ---------------- LIF update kernel ----------------
template <int G>
__global__ __launch_bounds__(256) void upd_kernel(
    const float* __restrict__ ext_exc,   // [T][BB][NE]
    const float* __restrict__ ext_inh,   // [T][BB][NI]
    const double* __restrict__ partial,  // [G][BB][NN]
    double* __restrict__ v,              // [BB][NN]
    float* __restrict__ sd,              // [BB][NN] fp32 spikes
    float* __restrict__ out,             // [T][BB][NN]
    int t)
{
    const int idx = blockIdx.x * 256 + threadIdx.x;   // < BB*NN
    const int b = idx / NN;
    const int n = idx - b * NN;

    const float ext = (n < NE)
        ? ext_exc[((size_t)t * BB + b) * NE + n]
        : ext_inh[((size_t)t * BB + b) * NI + (n - NE)];

    double acc = (double)ext;
#pragma unroll
    for (int g = 0; g < G; ++g)
        acc += partial[((size_t)g * BB + b) * NN + n];

    const double vv = v[idx] * 0.9 + acc;
    const double sp = (vv > 1.0) ? 1.0 : 0.0;
    out[(size_t)t * BB * NN + idx] = (float)sp;
    v[idx] = vv * (1.0 - sp);
    sd[idx] = (float)sp;
}

extern "C" void kernel_launch(void* const* d_in, const int* in_sizes, int n_in,
                              void* d_out, int out_size, void* d_ws, size_t ws_size,
                              hipStream_t stream) {
    const float* ext_exc = (const float*)d_in[0];
    const float* ext_inh = (const float*)d_in[1];
    const float* W_ee = (const float*)d_in[2];
    const float* W_ei = (const float*)d_in[3];
    const float* W_ie = (const float*)d_in[4];
    const float* W_ii = (const float*)d_in[5];
    float* out = (float*)d_out;

    const int T = in_sizes[0] / (BB * NE);   // 64

    const size_t SN = (size_t)BB * NN;       // 163840
    double* v = (double*)d_ws;               // [BB][NN] fp64
    float* sd = (float*)(v + SN);            // [BB][NN] fp32
    double* partial = (double*)(sd + SN);    // [G][BB][NN] fp64
    const size_t stateBytes = SN * 12;       // v + sd, ~2.0 MB

    // largest k-split G whose fp64 partial fits (round 5 proved G=32 fits)
    int G = 32;
    while (G > 8 && stateBytes + (size_t)G * SN * sizeof(double) > ws_size) G >>= 1;

    hipMemsetAsync(d_ws, 0, stateBytes, stream);   // v = 0, spikes = 0

    for (int t = 0; t < T; ++t) {
        switch (G) {
            case 32:
                mv_kernel<160> <<<dim3(HN/128, 32), 128, 0, stream>>>(W_ee, W_ei, W_ie, W_ii, sd, partial);
                upd_kernel<32><<<(int)(SN/256), 256, 0, stream>>>(ext_exc, ext_inh, partial, v, sd, out, t);
                break;
            case 16:
                mv_kernel<320> <<<dim3(HN/128, 16), 128, 0, stream>>>(W_ee, W_ei, W_ie, W_ii, sd, partial);
                upd_kernel<16><<<(int)(SN/256), 256, 0, stream>>>(ext_exc, ext_inh, partial, v, sd, out, t);
                break;
            default:
                mv_kernel<640> <<<dim3(HN/128, 8), 128, 0, stream>>>(W_ee, W_ei, W_ie, W_ii, sd, partial);
                upd_kernel<8> <<<(int)(SN/256), 256, 0, stream>>>(ext_exc, ext_inh, partial, v, sd, out, t);
                break;
        }
    }
}

// Round 9
// 4677.698 us; speedup vs baseline: 14.4308x; 14.4308x over previous
//
#include <hip/hip_runtime.h>

// Recurrent spiking LIF network: T=64, B=32, NE=4096, NI=1024, N=5120.
// Spikes exactly {0,1}; fp64 accumulation => spike-identical to the fp64
// numpy reference (verified rounds 2/5/6/7/8: absmax 0.0).
//
// Round-9: 2 neurons/thread WITHOUT the round-8 spill.
//  - Round-8 lesson: 64 fp64 accumulators (128 VGPR) spilled under a
//    128-reg cap -> 2.5 GB scratch traffic. Keep acc at 32 doubles.
//  - Block 256 thr = 128 n-threads x 2 j-halves: thread owns (nA, nA+2560)
//    and 16 batches. One shared 20 KB LDS stage serves both halves;
//    duplicate weight loads (t and t+128) are same-CU L1 hits.
//  - 1 ds_read_b128 feeds 8 FMAs (2n x 4k): LDS pipe 64 -> 32 us/step.
//  - G=32 k-split, KR=CHUNK=160: single stage pass; round-2 write pattern.

#define NE 4096
#define NI 1024
#define NN 5120
#define HN 2560      // NN/2
#define BB 32
#define JH 16        // batches per thread
#define CHUNK 160    // k-elements per LDS stage: 32*160*4 = 20 KB

// ---------------- matvec partial kernel ----------------
// grid: (HN/128, G), block 256. Thread (tn = t&127, jh = (t>>7)*16) owns
// neurons {nA = bx*128+tn, nA+2560} x batches [jh, jh+16) over KR sources.
template <int KR>
__global__ __launch_bounds__(256) void mv_kernel(
    const float* __restrict__ W_ee, const float* __restrict__ W_ei,
    const float* __restrict__ W_ie, const float* __restrict__ W_ii,
    const float* __restrict__ sd,    // [BB][NN] spikes fp32 (0.0/1.0)
    double* __restrict__ partial)    // [G][BB][NN]
{
    __shared__ float s_l[BB][CHUNK];
    const int t  = threadIdx.x;
    const int tn = t & 127;
    const int jh = (t >> 7) << 4;              // 0 or 16
    const int nA = blockIdx.x * 128 + tn;      // 0..2559 (< NE: E-target)
    const int nB = nA + HN;                    // 2560..5119 (mixed)
    const int kb0 = blockIdx.y * KR;

    double accA[JH], accB[JH];
#pragma unroll
    for (int j = 0; j < JH; ++j) { accA[j] = 0.0; accB[j] = 0.0; }

    const float* __restrict__ rEA = W_ee + (size_t)nA * NE;   // nA < NE
    const float* __restrict__ rIA = W_ie + (size_t)nA * NI;
    const float* __restrict__ rEB = (nB < NE) ? (W_ee + (size_t)nB * NE)
                                              : (W_ei + (size_t)(nB - NE) * NE);
    const float* __restrict__ rIB = (nB < NE) ? (W_ie + (size_t)nB * NI)
                                              : (W_ii + (size_t)(nB - NE) * NI);

    for (int pass = 0; pass < KR / CHUNK; ++pass) {
        const int kb = kb0 + pass * CHUNK;

        if (pass) __syncthreads();
        // stage 32 x 160 fp32 spikes, float4-vectorized (1280 quads / 256 thr)
        for (int f = t; f < BB * (CHUNK / 4); f += 256) {
            const int j = f / (CHUNK / 4);
            const int q = f - j * (CHUNK / 4);
            *reinterpret_cast<float4*>(&s_l[j][q * 4]) =
                *reinterpret_cast<const float4*>(sd + (size_t)j * NN + kb + q * 4);
        }
        __syncthreads();

        int aEnd = NE - kb;                    // E/I source boundary
        if (aEnd < 0) aEnd = 0;
        if (aEnd > CHUNK) aEnd = CHUNK;        // always a multiple of 4

        // ---- excitatory sources ----
        for (int kk = 0; kk < aEnd; kk += 4) {
            const float4 wa = *reinterpret_cast<const float4*>(rEA + kb + kk);
            const float4 wb = *reinterpret_cast<const float4*>(rEB + kb + kk);
            const double wa0 = (double)wa.x, wa1 = (double)wa.y,
                         wa2 = (double)wa.z, wa3 = (double)wa.w;
            const double wb0 = (double)wb.x, wb1 = (double)wb.y,
                         wb2 = (double)wb.z, wb3 = (double)wb.w;
#pragma unroll
            for (int j = 0; j < JH; ++j) {
                const float4 sv = *reinterpret_cast<const float4*>(&s_l[jh + j][kk]);
                const double s0 = (double)sv.x, s1 = (double)sv.y,
                             s2 = (double)sv.z, s3 = (double)sv.w;
                accA[j] += wa0 * s0 + wa1 * s1 + wa2 * s2 + wa3 * s3;
                accB[j] += wb0 * s0 + wb1 * s1 + wb2 * s2 + wb3 * s3;
            }
        }
        // ---- inhibitory sources ----
        for (int kk = aEnd; kk < CHUNK; kk += 4) {
            const int ki = kb + kk - NE;
            const float4 wa = *reinterpret_cast<const float4*>(rIA + ki);
            const float4 wb = *reinterpret_cast<const float4*>(rIB + ki);
            const double wa0 = (double)wa.x, wa1 = (double)wa.y,
                         wa2 = (double)wa.z, wa3 = (double)wa.w;
            const double wb0 = (double)wb.x, wb1 = (double)wb.y,
                         wb2 = (double)wb.z, wb3 = (double)wb.w;
#pragma unroll
            for (int j = 0; j < JH; ++j) {
                const float4 sv = *reinterpret_cast<const float4*>(&s_l[jh + j][kk]);
                const double s0 = (double)sv.x, s1 = (double)sv.y,
                             s2 = (double)sv.z, s3 = (double)sv.w;
                accA[j] += wa0 * s0 + wa1 * s1 + wa2 * s2 + wa3 * s3;
                accB[j] += wb0 * s0 + wb1 * s1 + wb2 * s2 + wb3 * s3;
            }
        }
    }

#pragma unroll
    for (int j = 0; j < JH; ++j) {
        const size_t base = ((size_t)blockIdx.y * BB + jh + j) * NN;
        partial[base + nA] = accA[j];
        partial[base + nB] = accB[j];
    }
}

// ---------------- LIF update kernel ----------------
template <int G>
__global__ __launch_bounds__(256) void upd_kernel(
    const float* __restrict__ ext_exc,   // [T][BB][NE]
    const float* __restrict__ ext_inh,   // [T][BB][NI]
    const double* __restrict__ partial,  // [G][BB][NN]
    double* __restrict__ v,              // [BB][NN]
    float* __restrict__ sd,              // [BB][NN] fp32 spikes
    float* __restrict__ out,             // [T][BB][NN]
    int t)
{
    const int idx = blockIdx.x * 256 + threadIdx.x;   // < BB*NN
    const int b = idx / NN;
    const int n = idx - b * NN;

    const float ext = (n < NE)
        ? ext_exc[((size_t)t * BB + b) * NE + n]
        : ext_inh[((size_t)t * BB + b) * NI + (n - NE)];

    double acc = (double)ext;
#pragma unroll
    for (int g = 0; g < G; ++g)
        acc += partial[((size_t)g * BB + b) * NN + n];

    const double vv = v[idx] * 0.9 + acc;
    const double sp = (vv > 1.0) ? 1.0 : 0.0;
    out[(size_t)t * BB * NN + idx] = (float)sp;
    v[idx] = vv * (1.0 - sp);
    sd[idx] = (float)sp;
}

extern "C" void kernel_launch(void* const* d_in, const int* in_sizes, int n_in,
                              void* d_out, int out_size, void* d_ws, size_t ws_size,
                              hipStream_t stream) {
    const float* ext_exc = (const float*)d_in[0];
    const float* ext_inh = (const float*)d_in[1];
    const float* W_ee = (const float*)d_in[2];
    const float* W_ei = (const float*)d_in[3];
    const float* W_ie = (const float*)d_in[4];
    const float* W_ii = (const float*)d_in[5];
    float* out = (float*)d_out;

    const int T = in_sizes[0] / (BB * NE);   // 64

    const size_t SN = (size_t)BB * NN;       // 163840
    double* v = (double*)d_ws;               // [BB][NN] fp64
    float* sd = (float*)(v + SN);            // [BB][NN] fp32
    double* partial = (double*)(sd + SN);    // [G][BB][NN] fp64
    const size_t stateBytes = SN * 12;       // v + sd, ~2.0 MB

    // largest k-split G whose fp64 partial fits (rounds 2/5/6 proved 44MB fits)
    int G = 32;
    while (G > 8 && stateBytes + (size_t)G * SN * sizeof(double) > ws_size) G >>= 1;

    hipMemsetAsync(d_ws, 0, stateBytes, stream);   // v = 0, spikes = 0

    for (int t = 0; t < T; ++t) {
        switch (G) {
            case 32:
                mv_kernel<160> <<<dim3(HN/128, 32), 256, 0, stream>>>(W_ee, W_ei, W_ie, W_ii, sd, partial);
                upd_kernel<32><<<(int)(SN/256), 256, 0, stream>>>(ext_exc, ext_inh, partial, v, sd, out, t);
                break;
            case 16:
                mv_kernel<320> <<<dim3(HN/128, 16), 256, 0, stream>>>(W_ee, W_ei, W_ie, W_ii, sd, partial);
                upd_kernel<16><<<(int)(SN/256), 256, 0, stream>>>(ext_exc, ext_inh, partial, v, sd, out, t);
                break;
            default:
                mv_kernel<640> <<<dim3(HN/128, 8), 256, 0, stream>>>(W_ee, W_ei, W_ie, W_ii, sd, partial);
                upd_kernel<8> <<<(int)(SN/256), 256, 0, stream>>>(ext_exc, ext_inh, partial, v, sd, out, t);
                break;
        }
    }
}